// Round 10
// baseline (68.825 us; speedup 1.0000x reference)
//
#include <hip/hip_runtime.h>
#include <cstddef>
#include <cstdint>

#define NROWS  200000
#define CIN    32
#define COUT   64
#define KV     27
#define NWAVES (NROWS / 64)   // 3125
#define WPB    12             // waves per block
#define TPB    768
#define KHALF  14             // idx LDS window (k 0..13, then 14..26)

typedef __attribute__((ext_vector_type(8))) short  short8;
typedef __attribute__((ext_vector_type(4))) float  f32x4;

// RNE float -> bf16 (inputs finite)
__device__ __forceinline__ unsigned short f2bf(float x) {
  unsigned u = __builtin_bit_cast(unsigned, x);
  u += 0x7FFFu + ((u >> 16) & 1u);
  return (unsigned short)(u >> 16);
}

// Pack weight [27][32][64] f32 -> bf16 B-fragments, mfma_16x16x32 B layout:
// wsB[(k*4+t)*64 + lane][f] = W[k][(lane>>4)*8+f][t*16+(lane&15)]
__global__ void prep_weight_kernel(const float* __restrict__ w,
                                   short8* __restrict__ wsB) {
  int tid = blockIdx.x * blockDim.x + threadIdx.x;   // 27*4*64 = 6912
  if (tid >= KV * 4 * 64) return;
  int lane = tid & 63;
  int t    = (tid >> 6) & 3;
  int k    = tid >> 8;
  int col  = t * 16 + (lane & 15);
  int kin0 = (lane >> 4) * 8;
  short8 v;
#pragma unroll
  for (int f = 0; f < 8; ++f)
    v[f] = (short)f2bf(w[((size_t)k * CIN + kin0 + f) * COUT + col]);
  wsB[tid] = v;
}

// feats f32 [N][32] -> bf16 [N+1][32]; row N (pad) = zeros.
__global__ void prep_feats_kernel(const float* __restrict__ feats,
                                  short8* __restrict__ fb) {
  int i = blockIdx.x * blockDim.x + threadIdx.x;
  const int total8 = (NROWS + 1) * CIN / 8;          // 800004
  if (i >= total8) return;
  short8 v = {0, 0, 0, 0, 0, 0, 0, 0};
  if (i < NROWS * CIN / 8) {
    const f32x4* p = (const f32x4*)feats + (size_t)i * 2;
    f32x4 a = p[0], b = p[1];
#pragma unroll
    for (int f = 0; f < 4; ++f) {
      v[f]     = (short)f2bf(a[f]);
      v[4 + f] = (short)f2bf(b[f]);
    }
  }
  fb[i] = v;
}

// Main: champion structure (Mw=4, idx-LDS) with B ELIMINATED from vmem:
// all 27x4 B-fragments (110,592 B) staged once per block in LDS, read via
// ds_read_b128 (LDS pipe) in the k-loop. Halves L2 read traffic (~338 MB of
// B re-loads gone) and halves per-iter vmem transactions (~128 -> ~65).
// 768-thread blocks (12 waves x 64 rows): 261 blocks = 1.02 dispatch rounds,
// 12 waves/CU, LDS 153.6 KB (B 110.6K + idx half-window 43K; idx staged in
// two halves per wave, no barrier needed after the initial one).
__global__ __launch_bounds__(TPB, 3)
void spconv_mfma_kernel(const unsigned short* __restrict__ featsbf,
                        const short8* __restrict__ wsB,
                        const float* __restrict__ bias,
                        const int* __restrict__ in_idx,
                        float* __restrict__ out) {
  __shared__ short8 sB[KV * 4 * 64];                 // 110,592 B
  __shared__ int sIdx[WPB][KHALF][64];               //  43,008 B

  const int tid = threadIdx.x;
  // cooperative B stage: 6912 fragments = 768 threads x 9
#pragma unroll
  for (int i = 0; i < 9; ++i)
    sB[i * TPB + tid] = wsB[i * TPB + tid];
  __syncthreads();

  const int lane = tid & 63;
  const int w    = tid >> 6;
  const int wid  = (int)blockIdx.x * WPB + w;
  if (wid >= NWAVES) return;                         // after the barrier
  const int row0 = wid << 6;

  const int c16  = lane & 15;
  const int kg   = lane >> 4;
  const int koff = kg * 8;

  // ---- stage idx half A (k=0..13) into per-wave LDS region ----
  {
    int tmp[KHALF];
#pragma unroll
    for (int k = 0; k < KHALF; ++k)
      tmp[k] = in_idx[(size_t)k * NROWS + row0 + lane];
#pragma unroll
    for (int k = 0; k < KHALF; ++k)
      sIdx[w][k][lane] = tmp[k];
  }

  f32x4 acc[4][4];                                   // [m][t]
#pragma unroll
  for (int t = 0; t < 4; ++t) {
    float bv = bias[t * 16 + c16];
    f32x4 bvv = {bv, bv, bv, bv};
#pragma unroll
    for (int m = 0; m < 4; ++m) acc[m][t] = bvv;
  }

  // ---- k-loop half A: k = 0..13 ----
  for (int k = 0; k < KHALF; ++k) {
    int idx[4];
#pragma unroll
    for (int m = 0; m < 4; ++m) idx[m] = sIdx[w][k][m * 16 + c16];

    short8 bfr[4];
#pragma unroll
    for (int t = 0; t < 4; ++t) bfr[t] = sB[(k * 4 + t) * 64 + lane];

    short8 afr[4];
#pragma unroll
    for (int m = 0; m < 4; ++m)
      afr[m] = *(const short8*)(featsbf + (size_t)idx[m] * CIN + koff);

#pragma unroll
    for (int m = 0; m < 4; ++m) {
      acc[m][0] = __builtin_amdgcn_mfma_f32_16x16x32_bf16(afr[m], bfr[0], acc[m][0], 0, 0, 0);
      acc[m][1] = __builtin_amdgcn_mfma_f32_16x16x32_bf16(afr[m], bfr[1], acc[m][1], 0, 0, 0);
      acc[m][2] = __builtin_amdgcn_mfma_f32_16x16x32_bf16(afr[m], bfr[2], acc[m][2], 0, 0, 0);
      acc[m][3] = __builtin_amdgcn_mfma_f32_16x16x32_bf16(afr[m], bfr[3], acc[m][3], 0, 0, 0);
    }
  }

  // ---- stage idx half B (k=14..26) into the same per-wave region ----
  // Same-wave ds ordering (write-after-read on sIdx) handled via lgkmcnt.
  {
    int tmp[KV - KHALF];
#pragma unroll
    for (int j = 0; j < KV - KHALF; ++j)
      tmp[j] = in_idx[(size_t)(KHALF + j) * NROWS + row0 + lane];
#pragma unroll
    for (int j = 0; j < KV - KHALF; ++j)
      sIdx[w][j][lane] = tmp[j];
  }

  // ---- k-loop half B: k = 14..26 ----
  for (int k = KHALF; k < KV; ++k) {
    int idx[4];
#pragma unroll
    for (int m = 0; m < 4; ++m) idx[m] = sIdx[w][k - KHALF][m * 16 + c16];

    short8 bfr[4];
#pragma unroll
    for (int t = 0; t < 4; ++t) bfr[t] = sB[(k * 4 + t) * 64 + lane];

    short8 afr[4];
#pragma unroll
    for (int m = 0; m < 4; ++m)
      afr[m] = *(const short8*)(featsbf + (size_t)idx[m] * CIN + koff);

#pragma unroll
    for (int m = 0; m < 4; ++m) {
      acc[m][0] = __builtin_amdgcn_mfma_f32_16x16x32_bf16(afr[m], bfr[0], acc[m][0], 0, 0, 0);
      acc[m][1] = __builtin_amdgcn_mfma_f32_16x16x32_bf16(afr[m], bfr[1], acc[m][1], 0, 0, 0);
      acc[m][2] = __builtin_amdgcn_mfma_f32_16x16x32_bf16(afr[m], bfr[2], acc[m][2], 0, 0, 0);
      acc[m][3] = __builtin_amdgcn_mfma_f32_16x16x32_bf16(afr[m], bfr[3], acc[m][3], 0, 0, 0);
    }
  }

  // D layout: col = t*16 + (lane&15), row = (lane>>4)*4 + r
#pragma unroll
  for (int m = 0; m < 4; ++m)
#pragma unroll
    for (int t = 0; t < 4; ++t)
#pragma unroll
      for (int r = 0; r < 4; ++r)
        out[(size_t)(row0 + m * 16 + kg * 4 + r) * COUT + t * 16 + c16] = acc[m][t][r];
}

// Correct-but-slow fallback if ws is tiny (shouldn't happen).
__global__ void spconv_naive_kernel(const float* __restrict__ feats,
                                    const float* __restrict__ w,
                                    const float* __restrict__ bias,
                                    const int* __restrict__ in_idx,
                                    float* __restrict__ out) {
  int gid = blockIdx.x * blockDim.x + threadIdx.x;
  if (gid >= NROWS * COUT) return;
  int row = gid / COUT, co = gid % COUT;
  float acc = bias[co];
  for (int k = 0; k < KV; ++k) {
    int idx = in_idx[(size_t)k * NROWS + row];
    if (idx < NROWS) {
      const float* fr = feats + (size_t)idx * CIN;
      const float* wk = w + (size_t)k * CIN * COUT + co;
#pragma unroll
      for (int c = 0; c < CIN; ++c) acc += fr[c] * wk[(size_t)c * COUT];
    }
  }
  out[gid] = acc;
}

extern "C" void kernel_launch(void* const* d_in, const int* in_sizes, int n_in,
                              void* d_out, int out_size, void* d_ws, size_t ws_size,
                              hipStream_t stream) {
  const float* feats  = (const float*)d_in[0];
  const float* weight = (const float*)d_in[1];
  const float* bias   = (const float*)d_in[2];
  const int*   in_idx = (const int*)d_in[3];
  float*       out    = (float*)d_out;

  const size_t wsB_bytes = (size_t)KV * 4 * 64 * 16;        // 110592
  const size_t fb_bytes  = (size_t)(NROWS + 1) * CIN * 2;   // 12800064
  short8*         wsB     = (short8*)d_ws;
  unsigned short* featsbf = (unsigned short*)((char*)d_ws + wsB_bytes);

  if (ws_size >= wsB_bytes + fb_bytes) {
    prep_weight_kernel<<<27, 256, 0, stream>>>(weight, wsB);
    prep_feats_kernel<<<((NROWS + 1) * CIN / 8 + 255) / 256, 256, 0, stream>>>(
        feats, (short8*)featsbf);
    const int blocks = (NWAVES + WPB - 1) / WPB;             // 261
    spconv_mfma_kernel<<<blocks, TPB, 0, stream>>>(
        featsbf, wsB, bias, in_idx, out);
  } else {
    spconv_naive_kernel<<<(NROWS * COUT + 255) / 256, 256, 0, stream>>>(
        feats, weight, bias, in_idx, out);
  }
}

// Round 11
// 57.723 us; speedup vs baseline: 1.1923x; 1.1923x over previous
//
#include <hip/hip_runtime.h>
#include <cstddef>
#include <cstdint>

#define NROWS  200000
#define CIN    32
#define COUT   64
#define KV     27
#define NWAVES (NROWS / 64)   // 3125

typedef __attribute__((ext_vector_type(8))) short  short8;
typedef __attribute__((ext_vector_type(4))) float  f32x4;

// RNE float -> bf16 (inputs finite)
__device__ __forceinline__ unsigned short f2bf(float x) {
  unsigned u = __builtin_bit_cast(unsigned, x);
  u += 0x7FFFu + ((u >> 16) & 1u);
  return (unsigned short)(u >> 16);
}

// Pack weight [27][32][64] f32 -> bf16 B-fragments, mfma_16x16x32 B layout:
// wsB[(k*4+t)*64 + lane][f] = W[k][(lane>>4)*8+f][t*16+(lane&15)]
__global__ void prep_weight_kernel(const float* __restrict__ w,
                                   short8* __restrict__ wsB) {
  int tid = blockIdx.x * blockDim.x + threadIdx.x;   // 27*4*64 = 6912
  if (tid >= KV * 4 * 64) return;
  int lane = tid & 63;
  int t    = (tid >> 6) & 3;
  int k    = tid >> 8;
  int col  = t * 16 + (lane & 15);
  int kin0 = (lane >> 4) * 8;
  short8 v;
#pragma unroll
  for (int f = 0; f < 8; ++f)
    v[f] = (short)f2bf(w[((size_t)k * CIN + kin0 + f) * COUT + col]);
  wsB[tid] = v;
}

// feats f32 [N][32] -> bf16 [N+1][32]; row N (pad) = zeros.
__global__ void prep_feats_kernel(const float* __restrict__ feats,
                                  short8* __restrict__ fb) {
  int i = blockIdx.x * blockDim.x + threadIdx.x;
  const int total8 = (NROWS + 1) * CIN / 8;          // 800004
  if (i >= total8) return;
  short8 v = {0, 0, 0, 0, 0, 0, 0, 0};
  if (i < NROWS * CIN / 8) {
    const f32x4* p = (const f32x4*)feats + (size_t)i * 2;
    f32x4 a = p[0], b = p[1];
#pragma unroll
    for (int f = 0; f < 4; ++f) {
      v[f]     = (short)f2bf(a[f]);
      v[4 + f] = (short)f2bf(b[f]);
    }
  }
  fb[i] = v;
}

// Main: champion structure (Mw=4, idx-LDS, 256-thread blocks) + per-iter
// double-buffered B staging. Per k the BLOCK stages the 4 KB B(k+1) slice
// into LDS once (256 thr x 16 B coalesced = 64 L2 lines vs 256 when every
// wave loads its own) and MFMAs read B(k) via ds_read_b128. Removes ~46% of
// L2 line-requests (the B re-read stream, 338 MB). LDS 35.8 KB -> 4
// blocks/CU -> up to 16 waves/CU (R10's 153 KB variant collapsed to 1
// block/CU + dispatch-tail disaster; this keeps the mechanism, fixes the
// geometry). One __syncthreads per iter; its vmcnt drain coincides with the
// wait the gather-consuming MFMAs need anyway.
__global__ __launch_bounds__(256, 4)
void spconv_mfma_kernel(const unsigned short* __restrict__ featsbf,
                        const short8* __restrict__ wsB,
                        const float* __restrict__ bias,
                        const int* __restrict__ in_idx,
                        float* __restrict__ out) {
  __shared__ short8 sB[2][256];                      //  8,192 B (dbuf B slice)
  __shared__ int sIdx[4][KV][64];                    // 27,648 B

  const int tid  = threadIdx.x;
  const int lane = tid & 63;
  const int w    = tid >> 6;
  // clamp (NOT return): 782*4=3128 waves vs 3125 tiles; the 3 surplus waves
  // recompute tile 3124 and store identical values (benign). No early exit
  // is allowed because of the per-iter barriers.
  int wid = (int)blockIdx.x * 4 + w;
  if (wid > NWAVES - 1) wid = NWAVES - 1;
  const int row0 = wid << 6;

  // ---- stage this wave's idx block into LDS (per-wave region) ----
  {
    int tmp[KV];
#pragma unroll
    for (int k = 0; k < KV; ++k)
      tmp[k] = in_idx[(size_t)k * NROWS + row0 + lane];
#pragma unroll
    for (int k = 0; k < KV; ++k)
      sIdx[w][k][lane] = tmp[k];
  }

  // ---- stage B(0) slice ----
  sB[0][tid] = wsB[tid];

  const int c16  = lane & 15;
  const int kg   = lane >> 4;
  const int koff = kg * 8;

  f32x4 acc[4][4];                                   // [m][t]
#pragma unroll
  for (int t = 0; t < 4; ++t) {
    float bv = bias[t * 16 + c16];
    f32x4 bvv = {bv, bv, bv, bv};
#pragma unroll
    for (int m = 0; m < 4; ++m) acc[m][t] = bvv;
  }

  __syncthreads();                                   // B(0) + idx visible

  for (int k = 0; k < KV; ++k) {
    // stage-load B(k+1) slice FIRST (head of vmem queue; drained for free by
    // the MFMAs' wait on the gathers, which sit behind it in the queue)
    short8 bst;
    if (k + 1 < KV) bst = wsB[(k + 1) * 256 + tid];

    int idx[4];
#pragma unroll
    for (int m = 0; m < 4; ++m) idx[m] = sIdx[w][k][m * 16 + c16];

    short8 afr[4];
#pragma unroll
    for (int m = 0; m < 4; ++m)
      afr[m] = *(const short8*)(featsbf + (size_t)idx[m] * CIN + koff);

    short8 bfr[4];
#pragma unroll
    for (int t = 0; t < 4; ++t) bfr[t] = sB[k & 1][t * 64 + lane];

#pragma unroll
    for (int m = 0; m < 4; ++m) {
      acc[m][0] = __builtin_amdgcn_mfma_f32_16x16x32_bf16(afr[m], bfr[0], acc[m][0], 0, 0, 0);
      acc[m][1] = __builtin_amdgcn_mfma_f32_16x16x32_bf16(afr[m], bfr[1], acc[m][1], 0, 0, 0);
      acc[m][2] = __builtin_amdgcn_mfma_f32_16x16x32_bf16(afr[m], bfr[2], acc[m][2], 0, 0, 0);
      acc[m][3] = __builtin_amdgcn_mfma_f32_16x16x32_bf16(afr[m], bfr[3], acc[m][3], 0, 0, 0);
    }

    // write staged B(k+1); buffer (k+1)&1 was last READ at iter k-1, and the
    // iter-(k-1) barrier ordered those reads before this write.
    if (k + 1 < KV) sB[(k + 1) & 1][tid] = bst;

    __syncthreads();
  }

  // D layout: col = t*16 + (lane&15), row = (lane>>4)*4 + r
#pragma unroll
  for (int m = 0; m < 4; ++m)
#pragma unroll
    for (int t = 0; t < 4; ++t)
#pragma unroll
      for (int r = 0; r < 4; ++r)
        out[(size_t)(row0 + m * 16 + kg * 4 + r) * COUT + t * 16 + c16] = acc[m][t][r];
}

// Correct-but-slow fallback if ws is tiny (shouldn't happen).
__global__ void spconv_naive_kernel(const float* __restrict__ feats,
                                    const float* __restrict__ w,
                                    const float* __restrict__ bias,
                                    const int* __restrict__ in_idx,
                                    float* __restrict__ out) {
  int gid = blockIdx.x * blockDim.x + threadIdx.x;
  if (gid >= NROWS * COUT) return;
  int row = gid / COUT, co = gid % COUT;
  float acc = bias[co];
  for (int k = 0; k < KV; ++k) {
    int idx = in_idx[(size_t)k * NROWS + row];
    if (idx < NROWS) {
      const float* fr = feats + (size_t)idx * CIN;
      const float* wk = w + (size_t)k * CIN * COUT + co;
#pragma unroll
      for (int c = 0; c < CIN; ++c) acc += fr[c] * wk[(size_t)c * COUT];
    }
  }
  out[gid] = acc;
}

extern "C" void kernel_launch(void* const* d_in, const int* in_sizes, int n_in,
                              void* d_out, int out_size, void* d_ws, size_t ws_size,
                              hipStream_t stream) {
  const float* feats  = (const float*)d_in[0];
  const float* weight = (const float*)d_in[1];
  const float* bias   = (const float*)d_in[2];
  const int*   in_idx = (const int*)d_in[3];
  float*       out    = (float*)d_out;

  const size_t wsB_bytes = (size_t)KV * 4 * 64 * 16;        // 110592
  const size_t fb_bytes  = (size_t)(NROWS + 1) * CIN * 2;   // 12800064
  short8*         wsB     = (short8*)d_ws;
  unsigned short* featsbf = (unsigned short*)((char*)d_ws + wsB_bytes);

  if (ws_size >= wsB_bytes + fb_bytes) {
    prep_weight_kernel<<<27, 256, 0, stream>>>(weight, wsB);
    prep_feats_kernel<<<((NROWS + 1) * CIN / 8 + 255) / 256, 256, 0, stream>>>(
        feats, (short8*)featsbf);
    const int blocks = (NWAVES + 3) / 4;                     // 782
    spconv_mfma_kernel<<<blocks, 256, 0, stream>>>(
        featsbf, wsB, bias, in_idx, out);
  } else {
    spconv_naive_kernel<<<(NROWS * COUT + 255) / 256, 256, 0, stream>>>(
        feats, weight, bias, in_idx, out);
  }
}